// Round 1
// baseline (4928.616 us; speedup 1.0000x reference)
//
#include <hip/hip_runtime.h>
#include <cstddef>

#define B_ 8
#define C_ 512
#define T_ 8192
#define ATT 1024   // outputs per activation block

// ---------------------------------------------------------------------------
// Fused Activation1d: upsample x2 (K=12 kaiser-sinc, replicate pad) ->
// SnakeBeta -> downsample x2 (K=12, replicate pad).
// Derived closed form (verified against the JAX reference algebra):
//   y[2q]   = 2 * sum_t x_c[q-3+t] * f[11-2t]     (t = 0..5)
//   y[2q+1] = 2 * sum_t x_c[q-2+t] * f[10-2t]
//   s(u)    = u + (1/(exp(lb)+1e-9)) * sin(u*exp(la))^2
//   z[m]    = sum_j g[j] * s(y[clamp(2m+j-5, 0, 2T-1)])
// x_c = replicate-clamped x.
// ---------------------------------------------------------------------------
__global__ __launch_bounds__(256) void act1d_kernel(
    const float* __restrict__ X,          // [B*C, T]
    const float* __restrict__ log_alpha,  // [C]
    const float* __restrict__ log_beta,   // [C]
    const float* __restrict__ fu,         // [12] up filter
    const float* __restrict__ fd,         // [12] down filter
    float* __restrict__ Z)                // [B*C, T]
{
    __shared__ float xs[ATT + 16];        // x[m0-8 .. m0+ATT+7] clamped
    __shared__ float ys[2 * ATT + 12];    // snaked y[n0 .. n0+2*ATT+11], n0 = 2*m0-5

    const int m0  = blockIdx.x * ATT;
    const int row = blockIdx.y;           // b*C + c
    const int c   = row & (C_ - 1);
    const int tid = threadIdx.x;
    const float* xr = X + (size_t)row * T_;

    float f[12], g[12];
#pragma unroll
    for (int j = 0; j < 12; ++j) { f[j] = fu[j]; g[j] = fd[j]; }
    const float alpha    = __expf(log_alpha[c]);
    const float inv_beta = 1.0f / (__expf(log_beta[c]) + 1e-9f);

    // stage x tile (replicate-clamped)
    for (int i = tid; i < ATT + 16; i += 256) {
        int xi = m0 - 8 + i;
        xi = min(max(xi, 0), T_ - 1);
        xs[i] = xr[xi];
    }
    __syncthreads();

    // compute snaked upsampled tile. n0 = 2*m0-5 is odd, so LDS index
    // i=2p is odd-n, i=2p+1 is even-n; both phases share xs[p+3 .. p+8].
    for (int p = tid; p < ATT + 6; p += 256) {
        const int base = p + 3;
        float uo = 0.0f, ue = 0.0f;
#pragma unroll
        for (int t = 0; t < 6; ++t) {
            const float xv = xs[base + t];
            uo += xv * f[10 - 2 * t];   // odd phase
            ue += xv * f[11 - 2 * t];   // even phase
        }
        uo *= 2.0f; ue *= 2.0f;
        const float so = __sinf(uo * alpha);
        const float se = __sinf(ue * alpha);
        ys[2 * p]     = uo + inv_beta * so * so;
        ys[2 * p + 1] = ue + inv_beta * se * se;
    }
    __syncthreads();

    // downsample
    float* zr = Z + (size_t)row * T_ + m0;
    const int n0 = 2 * m0 - 5;
    const bool interior = (m0 >= 3) && (m0 <= T_ - ATT - 3);
    if (interior) {
        for (int l = tid; l < ATT; l += 256) {
            float acc = 0.0f;
#pragma unroll
            for (int j = 0; j < 12; ++j) acc += g[j] * ys[2 * l + j];
            zr[l] = acc;
        }
    } else {
        for (int l = tid; l < ATT; l += 256) {
            const int m = m0 + l;
            float acc = 0.0f;
#pragma unroll
            for (int j = 0; j < 12; ++j) {
                int n = 2 * m + j - 5;
                n = min(max(n, 0), 2 * T_ - 1);
                acc += g[j] * ys[n - n0];
            }
            zr[l] = acc;
        }
    }
}

// ---------------------------------------------------------------------------
// Conv1d C->C, K=3, pad=1 (zero pad), optional residual add.
// O[b,o,t] = bias[o] + sum_{c,k} W[o,c,k] * Z[b,c,t+k-1]  (+ resid[b,o,t])
// Tiled fp32: 64(o) x 64(t) block tile, 4x4 per thread, 32-channel K-chunks.
// ---------------------------------------------------------------------------
__global__ __launch_bounds__(256) void conv3_kernel(
    const float* __restrict__ Zin,   // [B, C, T]
    const float* __restrict__ W,     // [C, C, 3]
    const float* __restrict__ bias,  // [C]
    const float* __restrict__ resid, // [B, C, T]
    float* __restrict__ Out,         // [B, C, T]
    const int addResid)
{
    __shared__ float Wl[32 * 3 * 64];   // [cc = c_local*3+k][o_local]
    __shared__ float Zl[32 * 72];       // [c_local][i], i -> t = t0-1+i, i in [0,66)

    const int t0  = blockIdx.x * 64;
    const int o0  = blockIdx.y * 64;
    const int b   = blockIdx.z;
    const int tid = threadIdx.x;
    const int tx  = tid & 15;           // t quarter
    const int ty  = tid >> 4;           // o quarter

    float acc[4][4] = {};

    const float* Zb = Zin + (size_t)b * C_ * T_;

    for (int c0 = 0; c0 < C_; c0 += 32) {
        __syncthreads();
        // --- stage W chunk: rows o0..o0+63, 96 contiguous floats each.
        // cc = c_local*3+k is exactly the raw column index -> no div/mod.
        for (int e = tid; e < 64 * 24; e += 256) {
            const int rowo = e / 24;
            const int col4 = e % 24;
            const float4 v = *(const float4*)(W + (size_t)(o0 + rowo) * (3 * C_) + c0 * 3 + col4 * 4);
            const float vv[4] = {v.x, v.y, v.z, v.w};
#pragma unroll
            for (int u = 0; u < 4; ++u) {
                const int cc = col4 * 4 + u;
                Wl[cc * 64 + rowo] = vv[u];
            }
        }
        // --- stage Z chunk: 32 rows x 66 cols (t0-1 .. t0+64), zero-padded.
        {
            const int lane = tid & 63;
            const int rgrp = tid >> 6;
            for (int rr = 0; rr < 32; rr += 4) {
                const int cl = rr + rgrp;
                const float* zrow = Zb + (size_t)(c0 + cl) * T_;
                const int t = t0 - 1 + lane;
                Zl[cl * 72 + lane] = (t >= 0 && t < T_) ? zrow[t] : 0.0f;
                if (lane < 2) {
                    const int t2 = t0 + 63 + lane;
                    Zl[cl * 72 + 64 + lane] = (t2 < T_) ? zrow[t2] : 0.0f;
                }
            }
        }
        __syncthreads();

#pragma unroll 2
        for (int c = 0; c < 32; ++c) {
            const float4 w0 = *(const float4*)&Wl[(c * 3 + 0) * 64 + ty * 4];
            const float4 w1 = *(const float4*)&Wl[(c * 3 + 1) * 64 + ty * 4];
            const float4 w2 = *(const float4*)&Wl[(c * 3 + 2) * 64 + ty * 4];
            const float4 z03 = *(const float4*)&Zl[c * 72 + tx * 4];
            const float2 z45 = *(const float2*)&Zl[c * 72 + tx * 4 + 4];
            const float zv[6] = {z03.x, z03.y, z03.z, z03.w, z45.x, z45.y};
            const float wa[3][4] = {{w0.x, w0.y, w0.z, w0.w},
                                    {w1.x, w1.y, w1.z, w1.w},
                                    {w2.x, w2.y, w2.z, w2.w}};
#pragma unroll
            for (int i = 0; i < 4; ++i)
#pragma unroll
                for (int j = 0; j < 4; ++j)
                    acc[i][j] += wa[0][i] * zv[j] + wa[1][i] * zv[j + 1] + wa[2][i] * zv[j + 2];
        }
    }

    // epilogue: bias (+ residual), coalesced float4 stores
#pragma unroll
    for (int i = 0; i < 4; ++i) {
        const int o = o0 + ty * 4 + i;
        const float bs = bias[o];
        const size_t off = ((size_t)b * C_ + o) * T_ + t0 + tx * 4;
        float4 v;
        v.x = acc[i][0] + bs;
        v.y = acc[i][1] + bs;
        v.z = acc[i][2] + bs;
        v.w = acc[i][3] + bs;
        if (addResid) {
            const float4 r = *(const float4*)(resid + off);
            v.x += r.x; v.y += r.y; v.z += r.z; v.w += r.w;
        }
        *(float4*)(Out + off) = v;
    }
}

extern "C" void kernel_launch(void* const* d_in, const int* in_sizes, int n_in,
                              void* d_out, int out_size, void* d_ws, size_t ws_size,
                              hipStream_t stream)
{
    const float* x   = (const float*)d_in[0];
    const float* a1a = (const float*)d_in[1];
    const float* a1b = (const float*)d_in[2];
    const float* a2a = (const float*)d_in[3];
    const float* a2b = (const float*)d_in[4];
    const float* c1w = (const float*)d_in[5];
    const float* c1b = (const float*)d_in[6];
    const float* c2w = (const float*)d_in[7];
    const float* c2b = (const float*)d_in[8];
    const float* fu  = (const float*)d_in[9];
    const float* fd  = (const float*)d_in[10];
    float* out = (float*)d_out;

    const size_t N = (size_t)B_ * C_ * T_;
    float* z1 = (float*)d_ws;       // act output buffer
    float* y1 = z1 + N;             // conv1 output buffer

    dim3 agrid(T_ / ATT, B_ * C_);
    dim3 cgrid(T_ / 64, C_ / 64, B_);

    // xt = act1(x)
    act1d_kernel<<<agrid, 256, 0, stream>>>(x, a1a, a1b, fu, fd, z1);
    // xt = conv1(xt)
    conv3_kernel<<<cgrid, 256, 0, stream>>>(z1, c1w, c1b, x, y1, 0);
    // xt = act2(xt)
    act1d_kernel<<<agrid, 256, 0, stream>>>(y1, a2a, a2b, fu, fd, z1);
    // out = conv2(xt) + x
    conv3_kernel<<<cgrid, 256, 0, stream>>>(z1, c2w, c2b, x, out, 1);
}

// Round 2
// 1742.917 us; speedup vs baseline: 2.8278x; 2.8278x over previous
//
#include <hip/hip_runtime.h>
#include <cstdint>
#include <cstddef>

#define B_ 8
#define C_ 512
#define T_ 8192

typedef unsigned short ushort_t;
typedef __attribute__((ext_vector_type(8))) short short8;            // 8 bf16 = 4 VGPR (MFMA A/B frag)
typedef __attribute__((ext_vector_type(8))) unsigned short ushort8_t;
typedef __attribute__((ext_vector_type(4))) float floatx4;           // MFMA C/D frag
typedef __attribute__((ext_vector_type(4))) unsigned int uintx4;

__device__ __forceinline__ ushort_t f2bf(float f) {
    // round-to-nearest-even fp32 -> bf16 (finite inputs)
    unsigned int u = __float_as_uint(f);
    u += 0x7FFFu + ((u >> 16) & 1u);
    return (ushort_t)(u >> 16);
}

// ---------------------------------------------------------------------------
// Fused Activation1d producing TRANSPOSED bf16 output z_T[b][t][c].
// Closed form verified in round 1:
//   y[2u]   = 2*sum_q x_c[u-3+q]*f[11-2q]
//   y[2u+1] = 2*sum_q x_c[u-2+q]*f[10-2q]
//   s(y)    = y + invb*sin(y*alpha)^2
//   z[t]    = sum_j g[j]*s(y[clamp(2t-5+j, 0, 2T-1)])
// Block: (t-tile of 16, b). 256 threads: tl=tid&15 (t), cg=tid>>4 (c stride 16).
// ---------------------------------------------------------------------------
__global__ __launch_bounds__(256) void act_t_kernel(
    const float* __restrict__ X,   // [B][C][T] fp32
    const float* __restrict__ la, const float* __restrict__ lb,
    const float* __restrict__ fu, const float* __restrict__ fd,
    ushort_t* __restrict__ Zt)     // [B][T][C] bf16
{
    __shared__ ushort_t zl[16 * 520];   // row stride 520 halves (1040B, 16B-aligned)

    const int t00 = blockIdx.x * 16;
    const int b   = blockIdx.y;
    const int tid = threadIdx.x;
    const int tl  = tid & 15;
    const int cg  = tid >> 4;
    const int t   = t00 + tl;

    float f[12], g[12];
#pragma unroll
    for (int j = 0; j < 12; ++j) { f[j] = fu[j]; g[j] = fd[j]; }

    const bool fast = (t >= 3) && (t <= T_ - 4);   // no y-index clamping needed

    for (int it = 0; it < 32; ++it) {
        const int c = cg + 16 * it;
        const float alpha = __expf(la[c]);
        const float invb  = 1.0f / (__expf(lb[c]) + 1e-9f);
        const float* xr = X + ((size_t)b * C_ + c) * T_;
        float zv = 0.0f;

        if (fast) {
            float xv[11];
#pragma unroll
            for (int o = 0; o < 11; ++o) {
                int xi = t - 5 + o;
                xi = min(max(xi, 0), T_ - 1);
                xv[o] = xr[xi];
            }
#pragma unroll
            for (int s = 0; s < 6; ++s) {
                float yo = 0.f, ye = 0.f;
#pragma unroll
                for (int q = 0; q < 6; ++q) {
                    yo += xv[s + q] * f[10 - 2 * q];
                    ye += xv[s + q] * f[11 - 2 * q];
                }
                yo *= 2.f; ye *= 2.f;
                const float so = __sinf(yo * alpha);
                const float se = __sinf(ye * alpha);
                yo += invb * so * so;
                ye += invb * se * se;
                zv += g[2 * s] * yo + g[2 * s + 1] * ye;
            }
        } else {
            // edge path: explicit y-index clamp, recompute y on demand
#pragma unroll
            for (int j = 0; j < 12; ++j) {
                int n = 2 * t - 5 + j;
                n = min(max(n, 0), 2 * T_ - 1);
                const int u = n >> 1;
                float y = 0.f;
                if (n & 1) {
#pragma unroll
                    for (int q = 0; q < 6; ++q) {
                        int xi = u - 2 + q; xi = min(max(xi, 0), T_ - 1);
                        y += xr[xi] * f[10 - 2 * q];
                    }
                } else {
#pragma unroll
                    for (int q = 0; q < 6; ++q) {
                        int xi = u - 3 + q; xi = min(max(xi, 0), T_ - 1);
                        y += xr[xi] * f[11 - 2 * q];
                    }
                }
                y *= 2.f;
                const float s = __sinf(y * alpha);
                y += invb * s * s;
                zv += g[j] * y;
            }
        }
        zl[tl * 520 + c] = f2bf(zv);
    }
    __syncthreads();

    // transpose-write: 16 rows of 1KB, 64 lanes x 16B fully coalesced
    const int q  = tid & 63;
    const int r4 = tid >> 6;
#pragma unroll
    for (int p = 0; p < 4; ++p) {
        const int r = p * 4 + r4;
        *(uintx4*)&Zt[((size_t)b * T_ + t00 + r) * C_ + q * 8] =
            *(const uintx4*)&zl[r * 520 + q * 8];
    }
}

// ---------------------------------------------------------------------------
// Pack W [o][c][k] fp32 -> MFMA-fragment-ordered bf16:
// Wb[(k*16+chunk)*32 + ot][lane][j] = W[ot*16+(lane&15)][chunk*32+(lane>>4)*8+j][k]
// One thread per 16B output segment. 98304 threads.
// ---------------------------------------------------------------------------
__global__ __launch_bounds__(256) void pack_w_kernel(
    const float* __restrict__ W, ushort_t* __restrict__ Wb)
{
    const int gid   = blockIdx.x * 256 + threadIdx.x;   // 0..98303
    const int lane  = gid & 63;
    const int rest  = gid >> 6;          // k*512 + chunk*32 + ot
    const int ot    = rest & 31;
    const int chunk = (rest >> 5) & 15;
    const int k     = rest >> 9;
    const int o     = ot * 16 + (lane & 15);
    const int c0    = chunk * 32 + (lane >> 4) * 8;
    ushort8_t v;
#pragma unroll
    for (int j = 0; j < 8; ++j)
        v[j] = f2bf(W[((size_t)o * C_ + c0 + j) * 3 + k]);
    *(ushort8_t*)&Wb[(size_t)gid * 8] = v;
}

// ---------------------------------------------------------------------------
// Conv1d C->C K=3 zero-pad as 3 shifted bf16 MFMA GEMMs, fp32 accumulate.
// O[o][t] = bias[o] + sum_k sum_c W[o][c][k] * z_T[t+k-1][c]   (+ resid)
// Block tile 128(o) x 128(t); 4 waves each 64x64 via 16x16x32_bf16.
// A staged with global_load_lds (frag-ordered Wb), B staged 130 rows x 32c.
// ---------------------------------------------------------------------------
__global__ __launch_bounds__(256) void conv_mfma_kernel(
    const ushort_t* __restrict__ Zt,   // [B][T][C] bf16
    const ushort_t* __restrict__ Wb,   // frag-packed weights
    const float* __restrict__ bias,
    const float* __restrict__ resid,
    float* __restrict__ Out,           // [B][C][T] fp32
    const int addResid)
{
    __shared__ __align__(16) ushort_t Al[3 * 8 * 512];   // 24KB: [k][ot][lane*8]
    __shared__ __align__(16) ushort_t Bl[130 * 40];      // 10.4KB: rows t0-1.., stride 40 halves

    const int t0  = blockIdx.x * 128;
    const int o0  = blockIdx.y * 128;
    const int b   = blockIdx.z;
    const int tid = threadIdx.x;
    const int lane = tid & 63;
    const int w    = tid >> 6;
    const int wo   = w & 1;        // o half
    const int wt   = w >> 1;       // t half

    const ushort_t* zb = Zt + (size_t)b * T_ * C_;

    floatx4 acc[4][4];
#pragma unroll
    for (int i = 0; i < 4; ++i)
#pragma unroll
        for (int j = 0; j < 4; ++j)
            acc[i][j] = (floatx4){0.f, 0.f, 0.f, 0.f};

    const int rB = tid >> 2;   // 0..63
    const int qB = tid & 3;

    for (int chunk = 0; chunk < 16; ++chunk) {
        const int c0 = chunk * 32;

        // --- A: async global->LDS, 24 segments of 1KB; wave w owns segs w*6..w*6+5
#pragma unroll
        for (int s = 0; s < 6; ++s) {
            const int seg = w * 6 + s;
            const int k   = seg >> 3;
            const int ot8 = seg & 7;
            const ushort_t* gsrc =
                Wb + (size_t)(((k * 16 + chunk) * 32) + (o0 >> 4) + ot8) * 512 + lane * 8;
            __builtin_amdgcn_global_load_lds(
                (const __attribute__((address_space(1))) unsigned int*)gsrc,
                (__attribute__((address_space(3))) unsigned int*)&Al[seg * 512],
                16, 0, 0);
        }

        // --- B: 130 rows (t0-1 .. t0+128) x 32 c, zero-padded at t edges
#pragma unroll
        for (int p = 0; p < 3; ++p) {
            const int r = rB + p * 64;
            if (r < 130) {
                const int t = t0 - 1 + r;
                uintx4 v = (uintx4){0u, 0u, 0u, 0u};
                if (t >= 0 && t < T_)
                    v = *(const uintx4*)&zb[(size_t)t * C_ + c0 + qB * 8];
                *(uintx4*)&Bl[r * 40 + qB * 8] = v;
            }
        }
        __syncthreads();

#pragma unroll
        for (int k = 0; k < 3; ++k) {
            short8 af[4], bf[4];
#pragma unroll
            for (int i = 0; i < 4; ++i)
                af[i] = *(const short8*)&Al[(k * 8 + wo * 4 + i) * 512 + lane * 8];
#pragma unroll
            for (int j = 0; j < 4; ++j)
                bf[j] = *(const short8*)&Bl[(wt * 64 + j * 16 + (lane & 15) + k) * 40 + (lane >> 4) * 8];
#pragma unroll
            for (int i = 0; i < 4; ++i)
#pragma unroll
                for (int j = 0; j < 4; ++j)
                    acc[i][j] = __builtin_amdgcn_mfma_f32_16x16x32_bf16(af[i], bf[j], acc[i][j], 0, 0, 0);
        }
        __syncthreads();
    }

    // --- epilogue: D[row=o][col=t], row=(lane>>4)*4+reg, col=lane&15
    const int tc0 = t0 + wt * 64 + (lane & 15);
#pragma unroll
    for (int i = 0; i < 4; ++i) {
        const int ob = o0 + wo * 64 + i * 16 + (lane >> 4) * 4;
#pragma unroll
        for (int r = 0; r < 4; ++r) {
            const int o = ob + r;
            const float bs = bias[o];
            const size_t rowoff = ((size_t)b * C_ + o) * T_;
#pragma unroll
            for (int j = 0; j < 4; ++j) {
                const int t = tc0 + j * 16;
                float v = acc[i][j][r] + bs;
                if (addResid) v += resid[rowoff + t];
                Out[rowoff + t] = v;
            }
        }
    }
}

extern "C" void kernel_launch(void* const* d_in, const int* in_sizes, int n_in,
                              void* d_out, int out_size, void* d_ws, size_t ws_size,
                              hipStream_t stream)
{
    const float* x   = (const float*)d_in[0];
    const float* a1a = (const float*)d_in[1];
    const float* a1b = (const float*)d_in[2];
    const float* a2a = (const float*)d_in[3];
    const float* a2b = (const float*)d_in[4];
    const float* c1w = (const float*)d_in[5];
    const float* c1b = (const float*)d_in[6];
    const float* c2w = (const float*)d_in[7];
    const float* c2b = (const float*)d_in[8];
    const float* fu  = (const float*)d_in[9];
    const float* fd  = (const float*)d_in[10];
    float* out = (float*)d_out;

    // workspace layout
    ushort_t* Zt  = (ushort_t*)d_ws;                                   // 67,108,864 B
    float*    y1  = (float*)((char*)d_ws + 67108864);                  // 134,217,728 B
    ushort_t* Wb1 = (ushort_t*)((char*)d_ws + 67108864 + 134217728);   // 1,572,864 B
    ushort_t* Wb2 = Wb1 + 786432;                                      // 1,572,864 B

    dim3 agrid(T_ / 16, B_);
    dim3 cgrid(T_ / 128, C_ / 128, B_);

    pack_w_kernel<<<384, 256, 0, stream>>>(c1w, Wb1);
    pack_w_kernel<<<384, 256, 0, stream>>>(c2w, Wb2);

    // xt = act1(x) -> z_T bf16
    act_t_kernel<<<agrid, 256, 0, stream>>>(x, a1a, a1b, fu, fd, Zt);
    // xt = conv1(xt) -> y1 fp32
    conv_mfma_kernel<<<cgrid, 256, 0, stream>>>(Zt, Wb1, c1b, x, y1, 0);
    // xt = act2(xt) -> z_T bf16
    act_t_kernel<<<agrid, 256, 0, stream>>>(y1, a2a, a2b, fu, fd, Zt);
    // out = conv2(xt) + x
    conv_mfma_kernel<<<cgrid, 256, 0, stream>>>(Zt, Wb2, c2b, x, out, 1);
}